// Round 5
// baseline (33348.276 us; speedup 1.0000x reference)
//
#include <hip/hip_runtime.h>
#include <stdint.h>

typedef unsigned long long u64;
typedef uint32_t u32;

#define NBLK   174
#define NT     256
#define TMAX   2048
#define EPROJS 1024
#define DUNITS 512
#define EMBED  512
#define JOINT  512
#define ODIM   10000

#define N_LSTM  32
#define B_DEC0  32
#define N_DEC   16
#define B_SCORE 48
#define B_CONS0 49
#define N_CONS  125         // 125 * 80 = 10000 rows
#define RPW     20          // logit rows per wave
#define MAGIC   0xD07ED07Eu
#define RMASK   3

// ws layout (bytes)
#define WS_YC    0          // u32[128]  y wave-counters (32 blk x 4 waves)
#define WS_ZC    512        // u32[64]   z wave-counters (16 blk x 4 waves)
#define WS_SP    768        // u32       scorer progress
#define WS_TRASH 832        // float     warming sink
#define WS_YB    1024       // f32[2][512] y payload ring
#define WS_ZB    5120       // f32[2][512] z payload ring
#define WS_PK    9216       // u64[4][128] packs ring (tag<<48|ord<<16|~row16)
#define WS_SM    13312      // u64[4][128] sums ring  (tag<<32|f32)
#define WS_DN    17408      // u32[256]  setup-done flags
#define WS_HP    32768      // float[2048*512] h_proj

__device__ __forceinline__ float aloadf(const float* p){
  return __hip_atomic_load(p, __ATOMIC_RELAXED, __HIP_MEMORY_SCOPE_AGENT);
}
__device__ __forceinline__ void astoref(float* p, float v){
  __hip_atomic_store(p, v, __ATOMIC_RELAXED, __HIP_MEMORY_SCOPE_AGENT);
}
__device__ __forceinline__ u64 aloadu64(const u64* p){
  return __hip_atomic_load(p, __ATOMIC_RELAXED, __HIP_MEMORY_SCOPE_AGENT);
}
__device__ __forceinline__ void astoreu64(u64* p, u64 v){
  __hip_atomic_store(p, v, __ATOMIC_RELAXED, __HIP_MEMORY_SCOPE_AGENT);
}
__device__ __forceinline__ u32 aloadu32(const u32* p){
  return __hip_atomic_load(p, __ATOMIC_RELAXED, __HIP_MEMORY_SCOPE_AGENT);
}
__device__ __forceinline__ void astoreu32(u32* p, u32 v){
  __hip_atomic_store(p, v, __ATOMIC_RELAXED, __HIP_MEMORY_SCOPE_AGENT);
}

__device__ __forceinline__ u32 ordbits(float f){
  u32 u = __float_as_uint(f);
  return (u & 0x80000000u) ? ~u : (u | 0x80000000u);
}
__device__ __forceinline__ float unordbits(u32 o){
  u32 u = (o & 0x80000000u) ? (o & 0x7fffffffu) : ~o;
  return __uint_as_float(u);
}
__device__ __forceinline__ float sigmoidf_(float x){ return 1.0f/(1.0f+expf(-x)); }

__device__ __forceinline__ float wredsum(float v){
  #pragma unroll
  for (int o=32;o>0;o>>=1) v += __shfl_xor(v, o);
  return v;
}
__device__ __forceinline__ u64 wredmax64(u64 v){
  #pragma unroll
  for (int o=32;o>0;o>>=1){ u64 x = __shfl_xor(v, o); v = (x>v)?x:v; }
  return v;
}

// wait until all 128 counters >= tg (2 coalesced loads/iter + backoff)
__device__ __forceinline__ void pollcnt128(const u32* c, int lane, u32 tg){
  for(;;){
    const u32 a = aloadu32(&c[lane]);
    const u32 b = aloadu32(&c[64+lane]);
    if (__all((a>=tg) & (b>=tg))) return;
    __builtin_amdgcn_s_sleep(2);
  }
}
// wait until all 64 counters >= tg (1 coalesced load/iter + backoff)
__device__ __forceinline__ void pollcnt64(const u32* c, int lane, u32 tg){
  for(;;){
    const u32 a = aloadu32(&c[lane]);
    if (__all(a>=tg)) return;
    __builtin_amdgcn_s_sleep(2);
  }
}
// read 512-f32 payload, strided ownership k=64j+lane
__device__ __forceinline__ void readpay8(const float* buf, int lane, float* o){
  #pragma unroll
  for (int j=0;j<8;j++) o[j] = aloadf(&buf[64*j + lane]);
}

__global__ void rnnt_init(char* ws){
  u32* p = (u32*)ws;
  for (int i = threadIdx.x; i < 4608; i += blockDim.x) p[i] = 0u;  // 18 KB control
}

__global__ void __launch_bounds__(NT, 1)
rnnt_decode(const float* __restrict__ h,    const float* __restrict__ embed,
            const float* __restrict__ W_ih, const float* __restrict__ W_hh,
            const float* __restrict__ b_ih, const float* __restrict__ b_hh,
            const float* __restrict__ W_enc,const float* __restrict__ b_enc,
            const float* __restrict__ W_dec,const float* __restrict__ W_out,
            const float* __restrict__ b_out,
            float* __restrict__ out, char* __restrict__ ws)
{
  const int b    = blockIdx.x;
  const int tid  = threadIdx.x;
  const int lane = tid & 63;
  const int w    = tid >> 6;

  u32*   ycnt  = (u32*)(ws + WS_YC);
  u32*   zcnt  = (u32*)(ws + WS_ZC);
  u32*   sprog = (u32*)(ws + WS_SP);
  float* trash = (float*)(ws + WS_TRASH);
  float* ybuf  = (float*)(ws + WS_YB);   // ring of 2 x 512
  float* zbuf  = (float*)(ws + WS_ZB);   // ring of 2 x 512
  u64*   packs = (u64*)(ws + WS_PK);     // ring of 4 x 128
  u64*   sums  = (u64*)(ws + WS_SM);     // ring of 4 x 128
  u32*   done  = (u32*)(ws + WS_DN);
  float* hp    = (float*)(ws + WS_HP);

  __shared__ float smem[8192];                 // 32 KB
  float* ZL = smem;                             // [512] z broadcast (cons)
  u64*   R64= (u64*)&smem[512];                 // 4 u64
  float* RF = &smem[520];                       // 4 floats

  // ========== setup: hp = h @ W_enc^T + b_enc, strips of 8 t-rows ==========
  {
    float (*lds_h)[EPROJS] = (float(*)[EPROJS])smem;
    for (int s = b; s < 256; s += NBLK){
      __syncthreads();
      #pragma unroll
      for (int r=0;r<8;r++){
        const float4 hv = *(const float4*)(h + (size_t)(8*s + r)*EPROJS + tid*4);
        *(float4*)&lds_h[r][tid*4] = hv;
      }
      __syncthreads();
      for (int p=0;p<2;p++){
        const int j = p*NT + tid;
        float acc[8] = {0,0,0,0,0,0,0,0};
        const float4* wrow = (const float4*)(W_enc + (size_t)j*EPROJS);
        for (int k4=0;k4<EPROJS/4;k4++){
          const float4 wv = wrow[k4];
          #pragma unroll
          for (int t8=0;t8<8;t8++){
            const float4 hv = *(const float4*)&lds_h[t8][k4*4];
            acc[t8] = fmaf(wv.x,hv.x, fmaf(wv.y,hv.y, fmaf(wv.z,hv.z, fmaf(wv.w,hv.w, acc[t8]))));
          }
        }
        const float be = b_enc[j];
        #pragma unroll
        for (int t8=0;t8<8;t8++)
          astoref(&hp[(size_t)(8*s+t8)*JOINT + j], acc[t8] + be);
      }
    }
    // warm the embed table into MALL (random rows hit it every step)
    {
      const size_t total4 = (size_t)ODIM*EMBED/4;
      const float4* e4 = (const float4*)embed;
      float acc = 0.f;
      for (size_t i = (size_t)b*NT + tid; i < total4; i += (size_t)NBLK*NT){
        const float4 v = e4[i];
        acc += v.x + v.y + v.z + v.w;
      }
      if (acc == 1.2345e-38f) astoref(trash, acc);   // never true; defeats DCE
    }
    asm volatile("s_waitcnt vmcnt(0)" ::: "memory");
    if (tid==0) astoreu32(&done[b], MAGIC);
    __syncthreads();   // smem reuse fence
  }

  // ============================ role: LSTM ===================================
  if (b < N_LSTM){
    const int d = b;
    float wih[16][8], whh[16][8], bias[16];
    #pragma unroll
    for (int m=0;m<16;m++){
      const int g = m>>2, j = m&3;
      const int r = g*DUNITS + 16*d + 4*w + j;
      #pragma unroll
      for (int k=0;k<8;k++){
        wih[m][k] = W_ih[(size_t)r*EMBED  + 64*k + lane];
        whh[m][k] = W_hh[(size_t)r*DUNITS + 64*k + lane];
      }
      bias[m] = b_ih[r] + b_hh[r];
    }
    float c_st[4], y_st[4];
    #pragma unroll
    for (int j=0;j<4;j++){
      c_st[j] = sigmoidf_(bias[j]) * tanhf(bias[8+j]);
      y_st[j] = sigmoidf_(bias[12+j]) * tanhf(c_st[j]);
    }
    // bootstrap: payload slot 0, counter = 1
    if (lane < 4){
      float yv = y_st[0];
      #pragma unroll
      for (int j=1;j<4;j++) if (lane==j) yv = y_st[j];
      astoref(&ybuf[16*d + 4*w + lane], yv);
    }
    asm volatile("s_waitcnt vmcnt(0)" ::: "memory");
    if (lane==0) astoreu32(&ycnt[4*d+w], 1u);

    for (int t=0;t<TMAX;t++){
      const u32 tg = (u32)(t+1);
      pollcnt128(ycnt, lane, tg);
      float y8[8]; readpay8(ybuf + (t&1)*512, lane, y8);
      float gt[16];
      #pragma unroll
      for (int m=0;m<16;m++){
        float a=0.f;
        #pragma unroll
        for (int k=0;k<8;k++) a = fmaf(whh[m][k], y8[k], a);
        gt[m] = wredsum(a) + bias[m];
      }
      // poll packs ring (tag-embedded, slot t&3)
      const u64* pk_s = packs + (t & RMASK)*128;
      u64 p0, p1;
      const u64 dummy = ((u64)tg << 48);
      for(;;){
        p0 = aloadu64(&pk_s[lane]);
        p1 = (lane < N_CONS-64) ? aloadu64(&pk_s[64+lane]) : dummy;
        if (__all(((u32)(p0>>48)==tg) & ((u32)(p1>>48)==tg))) break;
        __builtin_amdgcn_s_sleep(2);
      }
      u64 best = (p0>p1)?p0:p1;
      best = wredmax64(best);
      const int pred = (int)((~(u32)best) & 0xFFFFu);
      const int emitted = (pred != 0);
      float e8[8];
      #pragma unroll
      for (int k=0;k<8;k++) e8[k] = embed[(size_t)pred*EMBED + 64*k + lane];
      #pragma unroll
      for (int m=0;m<16;m++){
        float a=0.f;
        #pragma unroll
        for (int k=0;k<8;k++) a = fmaf(wih[m][k], e8[k], a);
        gt[m] += wredsum(a);
      }
      #pragma unroll
      for (int j=0;j<4;j++){
        const float gi=gt[j], gf=gt[4+j], gg=gt[8+j], go=gt[12+j];
        const float cn = sigmoidf_(gf)*c_st[j] + sigmoidf_(gi)*tanhf(gg);
        const float yn = sigmoidf_(go)*tanhf(cn);
        if (emitted){ c_st[j]=cn; y_st[j]=yn; }
      }
      if (lane < 4){
        float yv = y_st[0];
        #pragma unroll
        for (int j=1;j<4;j++) if (lane==j) yv = y_st[j];
        astoref(&ybuf[((t+1)&1)*512 + 16*d + 4*w + lane], yv);
      }
      asm volatile("s_waitcnt vmcnt(0)" ::: "memory");
      if (lane==0) astoreu32(&ycnt[4*d+w], tg+1u);
    }
  }
  // ============================ role: DEC ====================================
  else if (b < B_DEC0 + N_DEC){
    const int i = b - B_DEC0;
    float wdec[8][8];
    #pragma unroll
    for (int q=0;q<8;q++){
      const int r = 32*i + 8*w + q;
      #pragma unroll
      for (int k=0;k<8;k++) wdec[q][k] = W_dec[(size_t)r*DUNITS + 64*k + lane];
    }
    for(;;){
      const u32 d0 = aloadu32(&done[lane]);
      const u32 d1 = aloadu32(&done[64+lane]);
      const u32 d2 = (lane < NBLK-128) ? aloadu32(&done[128+lane]) : MAGIC;
      if (__all((d0==MAGIC) & (d1==MAGIC) & (d2==MAGIC))) break;
      __builtin_amdgcn_s_sleep(2);
    }
    for (int t=0;t<TMAX;t++){
      const u32 tg = (u32)(t+1);
      const float hpv = (lane<8) ? hp[(size_t)t*JOINT + 32*i + 8*w + lane] : 0.f;
      pollcnt128(ycnt, lane, tg);
      float y8[8]; readpay8(ybuf + (t&1)*512, lane, y8);
      float tot[8];
      #pragma unroll
      for (int q=0;q<8;q++){
        float a=0.f;
        #pragma unroll
        for (int k=0;k<8;k++) a = fmaf(wdec[q][k], y8[k], a);
        tot[q] = wredsum(a);
      }
      if (lane < 8){
        float u = tot[0];
        #pragma unroll
        for (int q=1;q<8;q++) if (lane==q) u = tot[q];
        astoref(&zbuf[(t&1)*512 + 32*i + 8*w + lane], tanhf(hpv + u));
      }
      asm volatile("s_waitcnt vmcnt(0)" ::: "memory");
      if (lane==0) astoreu32(&zcnt[4*i+w], tg);
    }
  }
  // ============================ role: SCORER =================================
  else if (b == B_SCORE){
    if (w == 0){
      float score = 0.0f;
      for (int t=0;t<TMAX;t++){
        const u32 tg = (u32)(t+1);
        const u64* pk_s = packs + (t & RMASK)*128;
        const u64* sm_s = sums  + (t & RMASK)*128;
        u64 p0=0,p1=0,s0=0,s1=0;
        const int v1 = (lane < N_CONS-64);
        for(;;){
          p0 = aloadu64(&pk_s[lane]);   s0 = aloadu64(&sm_s[lane]);
          int ok = ((u32)(p0>>48)==tg) & ((u32)(s0>>32)==tg);
          if (v1){
            p1 = aloadu64(&pk_s[64+lane]); s1 = aloadu64(&sm_s[64+lane]);
            ok &= ((u32)(p1>>48)==tg) & ((u32)(s1>>32)==tg);
          }
          if (__all(ok)) break;
          __builtin_amdgcn_s_sleep(8);
        }
        u64 best = (p0>p1)?p0:p1;
        best = wredmax64(best);
        const float mstar = unordbits((u32)(best>>16));
        const int pred = (int)((~(u32)best) & 0xFFFFu);
        float term = __uint_as_float((u32)s0) * __expf(unordbits((u32)(p0>>16)) - mstar);
        if (v1) term += __uint_as_float((u32)s1) * __expf(unordbits((u32)(p1>>16)) - mstar);
        term = wredsum(term);
        if (pred != 0) score += -logf(term);
        if (lane==0){
          out[t] = (float)pred;
          astoreu32(sprog, tg);          // ring overwrite gate progress
        }
      }
      if (lane==0) out[TMAX] = score;
    }
  }
  // ============================ role: CONSUMER ===============================
  else {
    const int cb = b - B_CONS0;
    const int rowstart = cb*80 + w*RPW;
    float wout[RPW][8]; float bo[RPW];
    #pragma unroll
    for (int q=0;q<RPW;q++){
      const int r = rowstart + q;
      #pragma unroll
      for (int k=0;k<8;k++) wout[q][k] = W_out[(size_t)r*JOINT + 64*k + lane];
      bo[q] = b_out[r];
    }
    for (int t=0;t<TMAX;t++){
      const u32 tg = (u32)(t+1);
      if (w == 0){
        pollcnt64(zcnt, lane, tg);
        float zs[8]; readpay8(zbuf + (t&1)*512, lane, zs);
        #pragma unroll
        for (int j=0;j<8;j++) ZL[64*j + lane] = zs[j];
      }
      __syncthreads();
      float z8[8];
      #pragma unroll
      for (int j=0;j<8;j++) z8[j] = ZL[64*j + lane];
      float lg[RPW];
      #pragma unroll
      for (int q=0;q<RPW;q++){
        float a=0.f;
        #pragma unroll
        for (int k=0;k<8;k++) a = fmaf(wout[q][k], z8[k], a);
        lg[q] = wredsum(a) + bo[q];
      }
      u64 bk = 0;
      #pragma unroll
      for (int q=0;q<RPW;q++){
        const u64 key = ((u64)ordbits(lg[q])<<16) | (u64)(0xFFFFu & ~(u32)(rowstart+q));
        bk = (key>bk)?key:bk;
      }
      const float mw = unordbits((u32)(bk>>16));
      float sw = 0.f;
      #pragma unroll
      for (int q=0;q<RPW;q++) sw += __expf(lg[q]-mw);
      if (lane==0){ R64[w] = bk; RF[w] = sw; }
      __syncthreads();
      if (tid==0){
        u64 bb = R64[0];
        #pragma unroll
        for (int k=1;k<4;k++) bb = (R64[k]>bb)?R64[k]:bb;
        const float mb = unordbits((u32)(bb>>16));
        float S = 0.f;
        #pragma unroll
        for (int k=0;k<4;k++) S += RF[k]*__expf(unordbits((u32)(R64[k]>>16)) - mb);
        while ((int)aloadu32(sprog) < t-3){ __builtin_amdgcn_s_sleep(4); }
        const int slot = t & RMASK;
        astoreu64(&sums [slot*128 + cb], ((u64)tg<<32) | (u64)__float_as_uint(S));
        astoreu64(&packs[slot*128 + cb], ((u64)tg<<48) | bb);
      }
    }
  }
}

extern "C" void kernel_launch(void* const* d_in, const int* in_sizes, int n_in,
                              void* d_out, int out_size, void* d_ws, size_t ws_size,
                              hipStream_t stream)
{
  const float* h     = (const float*)d_in[0];
  const float* embed = (const float*)d_in[1];
  const float* W_ih  = (const float*)d_in[2];
  const float* W_hh  = (const float*)d_in[3];
  const float* b_ih  = (const float*)d_in[4];
  const float* b_hh  = (const float*)d_in[5];
  const float* W_enc = (const float*)d_in[6];
  const float* b_enc = (const float*)d_in[7];
  const float* W_dec = (const float*)d_in[8];
  const float* W_out = (const float*)d_in[9];
  const float* b_out = (const float*)d_in[10];
  float* out = (float*)d_out;
  char* ws = (char*)d_ws;

  hipLaunchKernelGGL(rnnt_init, dim3(1), dim3(NT), 0, stream, ws);
  hipLaunchKernelGGL(rnnt_decode, dim3(NBLK), dim3(NT), 0, stream,
                     h, embed, W_ih, W_hh, b_ih, b_hh, W_enc, b_enc, W_dec, W_out, b_out,
                     out, ws);
}

// Round 6
// 23718.846 us; speedup vs baseline: 1.4060x; 1.4060x over previous
//
#include <hip/hip_runtime.h>
#include <stdint.h>

typedef unsigned long long u64;
typedef uint32_t u32;

#define NBLK   158
#define NT     256
#define TMAX   2048
#define EPROJS 1024
#define DUNITS 512
#define EMBED  512
#define JOINT  512
#define ODIM   10000

#define N_ST    32          // blocks 0..31: state (LSTM + W_dec/z)
#define B_SCORE 32          // block 32: scorer
#define B_CONS0 33          // blocks 33..157: consumers (W_out)
#define N_CONS  125         // 125 * 80 = 10000 rows
#define RPW     20          // logit rows per wave
#define MAGIC   0xD07ED07Eu
#define RMASK   3

// ws layout (bytes)
#define WS_YB    0          // u64[2][512] tagged y ring (tag<<32|f32)
#define WS_ZB    8192       // u64[2][512] tagged z ring
#define WS_PK    16384      // u64[4][128] packs ring (tag<<48|ord<<16|~row16)
#define WS_SM    20480      // u64[4][128] sums ring  (tag<<32|f32)
#define WS_DN    24576      // u32[256] setup-done flags
#define WS_SP    25600      // u32 scorer progress
#define WS_TRASH 25664      // float warming sink
#define WS_HP    32768      // float[2048*512] h_proj

__device__ __forceinline__ float aloadf(const float* p){
  return __hip_atomic_load(p, __ATOMIC_RELAXED, __HIP_MEMORY_SCOPE_AGENT);
}
__device__ __forceinline__ void astoref(float* p, float v){
  __hip_atomic_store(p, v, __ATOMIC_RELAXED, __HIP_MEMORY_SCOPE_AGENT);
}
__device__ __forceinline__ u64 aloadu64(const u64* p){
  return __hip_atomic_load(p, __ATOMIC_RELAXED, __HIP_MEMORY_SCOPE_AGENT);
}
__device__ __forceinline__ void astoreu64(u64* p, u64 v){
  __hip_atomic_store(p, v, __ATOMIC_RELAXED, __HIP_MEMORY_SCOPE_AGENT);
}
__device__ __forceinline__ u32 aloadu32(const u32* p){
  return __hip_atomic_load(p, __ATOMIC_RELAXED, __HIP_MEMORY_SCOPE_AGENT);
}
__device__ __forceinline__ void astoreu32(u32* p, u32 v){
  __hip_atomic_store(p, v, __ATOMIC_RELAXED, __HIP_MEMORY_SCOPE_AGENT);
}

__device__ __forceinline__ u32 ordbits(float f){
  u32 u = __float_as_uint(f);
  return (u & 0x80000000u) ? ~u : (u | 0x80000000u);
}
__device__ __forceinline__ float unordbits(u32 o){
  u32 u = (o & 0x80000000u) ? (o & 0x7fffffffu) : ~o;
  return __uint_as_float(u);
}
__device__ __forceinline__ float sigmoidf_(float x){ return 1.0f/(1.0f+expf(-x)); }

__device__ __forceinline__ float wredsum(float v){
  #pragma unroll
  for (int o=32;o>0;o>>=1) v += __shfl_xor(v, o);
  return v;
}
__device__ __forceinline__ u64 wredmax64(u64 v){
  #pragma unroll
  for (int o=32;o>0;o>>=1){ u64 x = __shfl_xor(v, o); v = (x>v)?x:v; }
  return v;
}

// poll 512-entry tagged buffer, lane-interleaved; payload floats for k=64j+lane
__device__ __forceinline__ void pollbuf8(const u64* buf, int lane, u32 tg, float* o){
  for(;;){
    u64 v[8];
    #pragma unroll
    for (int j=0;j<8;j++) v[j] = aloadu64(&buf[64*j + lane]);
    int ok = 1;
    #pragma unroll
    for (int j=0;j<8;j++) ok &= ((u32)(v[j]>>32) == tg);
    if (__all(ok)){
      #pragma unroll
      for (int j=0;j<8;j++) o[j] = __uint_as_float((u32)v[j]);
      return;
    }
  }
}

__global__ void rnnt_init(char* ws){
  u32* p = (u32*)ws;
  for (int i = threadIdx.x; i < 8192; i += blockDim.x) p[i] = 0u;  // 32 KB control
}

__global__ void __launch_bounds__(NT, 1)
rnnt_decode(const float* __restrict__ h,    const float* __restrict__ embed,
            const float* __restrict__ W_ih, const float* __restrict__ W_hh,
            const float* __restrict__ b_ih, const float* __restrict__ b_hh,
            const float* __restrict__ W_enc,const float* __restrict__ b_enc,
            const float* __restrict__ W_dec,const float* __restrict__ W_out,
            const float* __restrict__ b_out,
            float* __restrict__ out, char* __restrict__ ws)
{
  const int b    = blockIdx.x;
  const int tid  = threadIdx.x;
  const int lane = tid & 63;
  const int w    = tid >> 6;

  u64*   ybuf  = (u64*)(ws + WS_YB);     // ring 2 x 512
  u64*   zbuf  = (u64*)(ws + WS_ZB);     // ring 2 x 512
  u64*   packs = (u64*)(ws + WS_PK);     // ring 4 x 128
  u64*   sums  = (u64*)(ws + WS_SM);     // ring 4 x 128
  u32*   done  = (u32*)(ws + WS_DN);
  u32*   sprog = (u32*)(ws + WS_SP);
  float* trash = (float*)(ws + WS_TRASH);
  float* hp    = (float*)(ws + WS_HP);

  __shared__ float smem[8192];                 // 32 KB
  float* ZL = smem;                             // [512] z broadcast (cons)
  u64*   R64= (u64*)&smem[512];                 // 4 u64
  float* RF = &smem[520];                       // 4 floats

  // ========== setup: hp = h @ W_enc^T + b_enc, strips of 8 t-rows ==========
  {
    float (*lds_h)[EPROJS] = (float(*)[EPROJS])smem;
    for (int s = b; s < 256; s += NBLK){
      __syncthreads();
      #pragma unroll
      for (int r=0;r<8;r++){
        const float4 hv = *(const float4*)(h + (size_t)(8*s + r)*EPROJS + tid*4);
        *(float4*)&lds_h[r][tid*4] = hv;
      }
      __syncthreads();
      for (int p=0;p<2;p++){
        const int j = p*NT + tid;
        float acc[8] = {0,0,0,0,0,0,0,0};
        const float4* wrow = (const float4*)(W_enc + (size_t)j*EPROJS);
        for (int k4=0;k4<EPROJS/4;k4++){
          const float4 wv = wrow[k4];
          #pragma unroll
          for (int t8=0;t8<8;t8++){
            const float4 hv = *(const float4*)&lds_h[t8][k4*4];
            acc[t8] = fmaf(wv.x,hv.x, fmaf(wv.y,hv.y, fmaf(wv.z,hv.z, fmaf(wv.w,hv.w, acc[t8]))));
          }
        }
        const float be = b_enc[j];
        #pragma unroll
        for (int t8=0;t8<8;t8++)
          astoref(&hp[(size_t)(8*s+t8)*JOINT + j], acc[t8] + be);
      }
    }
    // warm the embed table into MALL (a random row is on the critical tail)
    {
      const size_t total4 = (size_t)ODIM*EMBED/4;
      const float4* e4 = (const float4*)embed;
      float acc = 0.f;
      for (size_t i = (size_t)b*NT + tid; i < total4; i += (size_t)NBLK*NT){
        const float4 v = e4[i];
        acc += v.x + v.y + v.z + v.w;
      }
      if (acc == 1.2345e-38f) astoref(trash, acc);   // never true; defeats DCE
    }
    asm volatile("s_waitcnt vmcnt(0)" ::: "memory");
    if (tid==0) astoreu32(&done[b], MAGIC);
    __syncthreads();   // smem reuse fence
  }

  // ============================ role: STATE (LSTM + z) =======================
  if (b < N_ST){
    const int d = b;
    // wave w owns y-elems 16d+4w+jj (jj<4); gate rows r = g*512 + 16d+4w+jj
    float wih[16][8], whh[16][8], bias[16], wdec4[4][8];
    #pragma unroll
    for (int m=0;m<16;m++){
      const int g = m>>2, jj = m&3;
      const int r = g*DUNITS + 16*d + 4*w + jj;
      #pragma unroll
      for (int k=0;k<8;k++){
        wih[m][k] = W_ih[(size_t)r*EMBED  + 64*k + lane];
        whh[m][k] = W_hh[(size_t)r*DUNITS + 64*k + lane];
      }
      bias[m] = b_ih[r] + b_hh[r];
    }
    #pragma unroll
    for (int jj=0;jj<4;jj++){
      const int zr = 16*d + 4*w + jj;
      #pragma unroll
      for (int k=0;k<8;k++) wdec4[jj][k] = W_dec[(size_t)zr*DUNITS + 64*k + lane];
    }
    // bootstrap state (x=0,h=0,c=0): gates = bias
    float c_st[4], y_st[4];
    #pragma unroll
    for (int jj=0;jj<4;jj++){
      c_st[jj] = sigmoidf_(bias[jj])    * tanhf(bias[8+jj]);
      y_st[jj] = sigmoidf_(bias[12+jj]) * tanhf(c_st[jj]);
    }
    if (lane < 4){
      float yv = y_st[0];
      #pragma unroll
      for (int jj=1;jj<4;jj++) if (lane==jj) yv = y_st[jj];
      astoreu64(&ybuf[16*d + 4*w + lane], ((u64)1u<<32) | (u64)__float_as_uint(yv));
    }
    // wait for hp writers (all NBLK blocks)
    for(;;){
      const u32 d0 = aloadu32(&done[lane]);
      const u32 d1 = aloadu32(&done[64+lane]);
      const u32 d2 = (lane < NBLK-128) ? aloadu32(&done[128+lane]) : MAGIC;
      if (__all((d0==MAGIC) & (d1==MAGIC) & (d2==MAGIC))) break;
    }

    for (int t=0;t<TMAX;t++){
      const u32 tg = (u32)(t+1);
      // prefetch hp value for our z-row (overlaps the y poll)
      const float hpv = aloadf(&hp[(size_t)t*JOINT + 16*d + 4*w + (lane&3)]);
      float y8[8]; pollbuf8(ybuf + (t&1)*512, lane, tg, y8);
      // ---- critical: publish z(t) ----
      float zz[4];
      #pragma unroll
      for (int jj=0;jj<4;jj++){
        float a=0.f;
        #pragma unroll
        for (int k=0;k<8;k++) a = fmaf(wdec4[jj][k], y8[k], a);
        zz[jj] = wredsum(a);
      }
      if (lane < 4){
        float uv = zz[0];
        #pragma unroll
        for (int jj=1;jj<4;jj++) if (lane==jj) uv = zz[jj];
        astoreu64(&zbuf[(t&1)*512 + 16*d + 4*w + lane],
                  ((u64)tg<<32) | (u64)__float_as_uint(tanhf(hpv + uv)));
      }
      // ---- off-critical: W_hh @ y (overlaps z->packs latency) ----
      float gt[16];
      #pragma unroll
      for (int m=0;m<16;m++){
        float a=0.f;
        #pragma unroll
        for (int k=0;k<8;k++) a = fmaf(whh[m][k], y8[k], a);
        gt[m] = wredsum(a) + bias[m];
      }
      // ---- poll packs(t) ----
      const u64* pk_s = packs + (t & RMASK)*128;
      u64 p0, p1;
      const u64 dummy = ((u64)tg << 48);
      for(;;){
        p0 = aloadu64(&pk_s[lane]);
        p1 = (lane < N_CONS-64) ? aloadu64(&pk_s[64+lane]) : dummy;
        if (__all(((u32)(p0>>48)==tg) & ((u32)(p1>>48)==tg))) break;
      }
      u64 best = (p0>p1)?p0:p1;
      best = wredmax64(best);
      const int pred = (int)((~(u32)best) & 0xFFFFu);
      const int emitted = (pred != 0);
      // ---- gates += W_ih @ embed[pred]; nonlinearity; publish y(t+1) ----
      float e8[8];
      #pragma unroll
      for (int k=0;k<8;k++) e8[k] = embed[(size_t)pred*EMBED + 64*k + lane];
      #pragma unroll
      for (int m=0;m<16;m++){
        float a=0.f;
        #pragma unroll
        for (int k=0;k<8;k++) a = fmaf(wih[m][k], e8[k], a);
        gt[m] += wredsum(a);
      }
      #pragma unroll
      for (int jj=0;jj<4;jj++){
        const float gi=gt[jj], gf=gt[4+jj], gg=gt[8+jj], go=gt[12+jj];
        const float cn = sigmoidf_(gf)*c_st[jj] + sigmoidf_(gi)*tanhf(gg);
        const float yn = sigmoidf_(go)*tanhf(cn);
        if (emitted){ c_st[jj]=cn; y_st[jj]=yn; }
      }
      if (t+1 < TMAX && lane < 4){
        float yv = y_st[0];
        #pragma unroll
        for (int jj=1;jj<4;jj++) if (lane==jj) yv = y_st[jj];
        astoreu64(&ybuf[((t+1)&1)*512 + 16*d + 4*w + lane],
                  ((u64)(tg+1)<<32) | (u64)__float_as_uint(yv));
      }
    }
  }
  // ============================ role: SCORER =================================
  else if (b == B_SCORE){
    if (w == 0){
      float score = 0.0f;
      for (int t=0;t<TMAX;t++){
        const u32 tg = (u32)(t+1);
        const u64* pk_s = packs + (t & RMASK)*128;
        const u64* sm_s = sums  + (t & RMASK)*128;
        u64 p0=0,p1=0,s0=0,s1=0;
        const int v1 = (lane < N_CONS-64);
        for(;;){
          p0 = aloadu64(&pk_s[lane]);   s0 = aloadu64(&sm_s[lane]);
          int ok = ((u32)(p0>>48)==tg) & ((u32)(s0>>32)==tg);
          if (v1){
            p1 = aloadu64(&pk_s[64+lane]); s1 = aloadu64(&sm_s[64+lane]);
            ok &= ((u32)(p1>>48)==tg) & ((u32)(s1>>32)==tg);
          }
          if (__all(ok)) break;
          __builtin_amdgcn_s_sleep(8);
        }
        u64 best = (p0>p1)?p0:p1;
        best = wredmax64(best);
        const float mstar = unordbits((u32)(best>>16));
        const int pred = (int)((~(u32)best) & 0xFFFFu);
        float term = __uint_as_float((u32)s0) * __expf(unordbits((u32)(p0>>16)) - mstar);
        if (v1) term += __uint_as_float((u32)s1) * __expf(unordbits((u32)(p1>>16)) - mstar);
        term = wredsum(term);
        if (pred != 0) score += -logf(term);
        if (lane==0){
          out[t] = (float)pred;
          astoreu32(sprog, tg);          // ring overwrite gate progress
        }
      }
      if (lane==0) out[TMAX] = score;
    }
  }
  // ============================ role: CONSUMER ===============================
  else {
    const int cb = b - B_CONS0;
    const int rowstart = cb*80 + w*RPW;
    float wout[RPW][8]; float bo[RPW];
    #pragma unroll
    for (int q=0;q<RPW;q++){
      const int r = rowstart + q;
      #pragma unroll
      for (int k=0;k<8;k++) wout[q][k] = W_out[(size_t)r*JOINT + 64*k + lane];
      bo[q] = b_out[r];
    }
    for (int t=0;t<TMAX;t++){
      const u32 tg = (u32)(t+1);
      if (w == 0){
        float zs[8]; pollbuf8(zbuf + (t&1)*512, lane, tg, zs);
        #pragma unroll
        for (int j=0;j<8;j++) ZL[64*j + lane] = zs[j];
      }
      __syncthreads();
      float z8[8];
      #pragma unroll
      for (int j=0;j<8;j++) z8[j] = ZL[64*j + lane];
      float lg[RPW];
      #pragma unroll
      for (int q=0;q<RPW;q++){
        float a=0.f;
        #pragma unroll
        for (int k=0;k<8;k++) a = fmaf(wout[q][k], z8[k], a);
        lg[q] = wredsum(a) + bo[q];
      }
      u64 bk = 0;
      #pragma unroll
      for (int q=0;q<RPW;q++){
        const u64 key = ((u64)ordbits(lg[q])<<16) | (u64)(0xFFFFu & ~(u32)(rowstart+q));
        bk = (key>bk)?key:bk;
      }
      const float mw = unordbits((u32)(bk>>16));
      float sw = 0.f;
      #pragma unroll
      for (int q=0;q<RPW;q++) sw += __expf(lg[q]-mw);
      if (lane==0){ R64[w] = bk; RF[w] = sw; }
      __syncthreads();
      if (tid==0){
        u64 bb = R64[0];
        #pragma unroll
        for (int k=1;k<4;k++) bb = (R64[k]>bb)?R64[k]:bb;
        const float mb = unordbits((u32)(bb>>16));
        float S = 0.f;
        #pragma unroll
        for (int k=0;k<4;k++) S += RF[k]*__expf(unordbits((u32)(R64[k]>>16)) - mb);
        // ring overwrite gate: scorer must have finished step t-4's slot
        while ((int)aloadu32(sprog) < t-3){ __builtin_amdgcn_s_sleep(4); }
        const int slot = t & RMASK;
        astoreu64(&sums [slot*128 + cb], ((u64)tg<<32) | (u64)__float_as_uint(S));
        astoreu64(&packs[slot*128 + cb], ((u64)tg<<48) | bb);
      }
    }
  }
}

extern "C" void kernel_launch(void* const* d_in, const int* in_sizes, int n_in,
                              void* d_out, int out_size, void* d_ws, size_t ws_size,
                              hipStream_t stream)
{
  const float* h     = (const float*)d_in[0];
  const float* embed = (const float*)d_in[1];
  const float* W_ih  = (const float*)d_in[2];
  const float* W_hh  = (const float*)d_in[3];
  const float* b_ih  = (const float*)d_in[4];
  const float* b_hh  = (const float*)d_in[5];
  const float* W_enc = (const float*)d_in[6];
  const float* b_enc = (const float*)d_in[7];
  const float* W_dec = (const float*)d_in[8];
  const float* W_out = (const float*)d_in[9];
  const float* b_out = (const float*)d_in[10];
  float* out = (float*)d_out;
  char* ws = (char*)d_ws;

  hipLaunchKernelGGL(rnnt_init, dim3(1), dim3(NT), 0, stream, ws);
  hipLaunchKernelGGL(rnnt_decode, dim3(NBLK), dim3(NT), 0, stream,
                     h, embed, W_ih, W_hh, b_ih, b_hh, W_enc, b_enc, W_dec, W_out, b_out,
                     out, ws);
}

// Round 7
// 20064.064 us; speedup vs baseline: 1.6621x; 1.1822x over previous
//
#include <hip/hip_runtime.h>
#include <stdint.h>

typedef unsigned long long u64;
typedef uint32_t u32;

#define NBLK   190
#define NT     256
#define TMAX   2048
#define EPROJS 1024
#define DUNITS 512
#define EMBED  512
#define JOINT  512
#define ODIM   10000

#define N_ST    64          // blocks 0..63: state (LSTM + W_dec/z), 8 y-elems each
#define B_SCORE 64          // block 64: scorer
#define B_CONS0 65          // blocks 65..189: consumers (W_out)
#define N_CONS  125         // 125 * 80 = 10000 rows
#define RPW     20          // logit rows per wave
#define MAGIC   0xD07ED07Eu
#define RMASK   3

// ws layout (bytes)
#define WS_YB    0          // u64[2][512] tagged y ring (tag<<32|f32)
#define WS_ZR    8192       // u64[4][2][512] tagged z ring, 4 replicas (32 KB)
#define WS_PK    40960      // u64[4][128] packs ring (tag<<48|ord<<16|~row16)
#define WS_SM    45056      // u64[4][128] sums ring  (tag<<32|f32)
#define WS_DN    49152      // u32[256] setup-done flags
#define WS_SP    50176      // u32 scorer progress
#define WS_TRASH 50240      // float warming sink
#define WS_HP    65536      // float[2048*512] h_proj

__device__ __forceinline__ float aloadf(const float* p){
  return __hip_atomic_load(p, __ATOMIC_RELAXED, __HIP_MEMORY_SCOPE_AGENT);
}
__device__ __forceinline__ void astoref(float* p, float v){
  __hip_atomic_store(p, v, __ATOMIC_RELAXED, __HIP_MEMORY_SCOPE_AGENT);
}
__device__ __forceinline__ u64 aloadu64(const u64* p){
  return __hip_atomic_load(p, __ATOMIC_RELAXED, __HIP_MEMORY_SCOPE_AGENT);
}
__device__ __forceinline__ void astoreu64(u64* p, u64 v){
  __hip_atomic_store(p, v, __ATOMIC_RELAXED, __HIP_MEMORY_SCOPE_AGENT);
}
__device__ __forceinline__ u32 aloadu32(const u32* p){
  return __hip_atomic_load(p, __ATOMIC_RELAXED, __HIP_MEMORY_SCOPE_AGENT);
}
__device__ __forceinline__ void astoreu32(u32* p, u32 v){
  __hip_atomic_store(p, v, __ATOMIC_RELAXED, __HIP_MEMORY_SCOPE_AGENT);
}

__device__ __forceinline__ u32 ordbits(float f){
  u32 u = __float_as_uint(f);
  return (u & 0x80000000u) ? ~u : (u | 0x80000000u);
}
__device__ __forceinline__ float unordbits(u32 o){
  u32 u = (o & 0x80000000u) ? (o & 0x7fffffffu) : ~o;
  return __uint_as_float(u);
}
__device__ __forceinline__ float sigmoidf_(float x){ return 1.0f/(1.0f+expf(-x)); }

__device__ __forceinline__ float wredsum(float v){
  #pragma unroll
  for (int o=32;o>0;o>>=1) v += __shfl_xor(v, o);
  return v;
}
__device__ __forceinline__ u64 wredmax64(u64 v){
  #pragma unroll
  for (int o=32;o>0;o>>=1){ u64 x = __shfl_xor(v, o); v = (x>v)?x:v; }
  return v;
}

// poll 512-entry tagged buffer, lane-interleaved; payload floats for k=64j+lane
__device__ __forceinline__ void pollbuf8(const u64* buf, int lane, u32 tg, float* o){
  for(;;){
    u64 v[8];
    #pragma unroll
    for (int j=0;j<8;j++) v[j] = aloadu64(&buf[64*j + lane]);
    int ok = 1;
    #pragma unroll
    for (int j=0;j<8;j++) ok &= ((u32)(v[j]>>32) == tg);
    if (__all(ok)){
      #pragma unroll
      for (int j=0;j<8;j++) o[j] = __uint_as_float((u32)v[j]);
      return;
    }
  }
}

__global__ void rnnt_init(char* ws){
  u32* p = (u32*)ws;
  for (int i = threadIdx.x; i < 16384; i += blockDim.x) p[i] = 0u;  // 64 KB control
}

__global__ void __launch_bounds__(NT, 1)
rnnt_decode(const float* __restrict__ h,    const float* __restrict__ embed,
            const float* __restrict__ W_ih, const float* __restrict__ W_hh,
            const float* __restrict__ b_ih, const float* __restrict__ b_hh,
            const float* __restrict__ W_enc,const float* __restrict__ b_enc,
            const float* __restrict__ W_dec,const float* __restrict__ W_out,
            const float* __restrict__ b_out,
            float* __restrict__ out, char* __restrict__ ws)
{
  const int b    = blockIdx.x;
  const int tid  = threadIdx.x;
  const int lane = tid & 63;
  const int w    = tid >> 6;

  u64*   ybuf  = (u64*)(ws + WS_YB);     // ring 2 x 512
  u64*   zrep  = (u64*)(ws + WS_ZR);     // 4 replicas x ring 2 x 512
  u64*   packs = (u64*)(ws + WS_PK);     // ring 4 x 128
  u64*   sums  = (u64*)(ws + WS_SM);     // ring 4 x 128
  u32*   done  = (u32*)(ws + WS_DN);
  u32*   sprog = (u32*)(ws + WS_SP);
  float* trash = (float*)(ws + WS_TRASH);
  float* hp    = (float*)(ws + WS_HP);

  __shared__ float smem[8192];                 // 32 KB
  float* YL = smem;                             // [512] y broadcast (state)
  float* ZL = smem;                             // [512] z broadcast (cons)
  u64*   R64= (u64*)&smem[512];                 // 4 u64
  float* RF = &smem[520];                       // 4 floats
  int*   PRD= (int*)&smem[524];                 // pred broadcast

  // ========== setup: hp = h @ W_enc^T + b_enc, strips of 8 t-rows ==========
  {
    float (*lds_h)[EPROJS] = (float(*)[EPROJS])smem;
    for (int s = b; s < 256; s += NBLK){
      __syncthreads();
      #pragma unroll
      for (int r=0;r<8;r++){
        const float4 hv = *(const float4*)(h + (size_t)(8*s + r)*EPROJS + tid*4);
        *(float4*)&lds_h[r][tid*4] = hv;
      }
      __syncthreads();
      for (int p=0;p<2;p++){
        const int j = p*NT + tid;
        float acc[8] = {0,0,0,0,0,0,0,0};
        const float4* wrow = (const float4*)(W_enc + (size_t)j*EPROJS);
        for (int k4=0;k4<EPROJS/4;k4++){
          const float4 wv = wrow[k4];
          #pragma unroll
          for (int t8=0;t8<8;t8++){
            const float4 hv = *(const float4*)&lds_h[t8][k4*4];
            acc[t8] = fmaf(wv.x,hv.x, fmaf(wv.y,hv.y, fmaf(wv.z,hv.z, fmaf(wv.w,hv.w, acc[t8]))));
          }
        }
        const float be = b_enc[j];
        #pragma unroll
        for (int t8=0;t8<8;t8++)
          astoref(&hp[(size_t)(8*s+t8)*JOINT + j], acc[t8] + be);
      }
    }
    // warm the embed table into MALL (a random row is on the critical tail)
    {
      const size_t total4 = (size_t)ODIM*EMBED/4;
      const float4* e4 = (const float4*)embed;
      float acc = 0.f;
      for (size_t i = (size_t)b*NT + tid; i < total4; i += (size_t)NBLK*NT){
        const float4 v = e4[i];
        acc += v.x + v.y + v.z + v.w;
      }
      if (acc == 1.2345e-38f) astoref(trash, acc);   // never true; defeats DCE
    }
    asm volatile("s_waitcnt vmcnt(0)" ::: "memory");
    if (tid==0) astoreu32(&done[b], MAGIC);
    __syncthreads();   // smem reuse fence
  }

  // ============================ role: STATE (LSTM + z) =======================
  if (b < N_ST){
    const int d = b;
    // wave w owns y-elems 8d+2w+jj (jj<2); gate rows r = g*512 + 8d+2w+jj
    float wih[8][8], whh[8][8], bias[8], wdec2[2][8];
    #pragma unroll
    for (int m=0;m<8;m++){
      const int g = m>>1, jj = m&1;
      const int r = g*DUNITS + 8*d + 2*w + jj;
      #pragma unroll
      for (int k=0;k<8;k++){
        wih[m][k] = W_ih[(size_t)r*EMBED  + 64*k + lane];
        whh[m][k] = W_hh[(size_t)r*DUNITS + 64*k + lane];
      }
      bias[m] = b_ih[r] + b_hh[r];
    }
    #pragma unroll
    for (int jj=0;jj<2;jj++){
      const int zr = 8*d + 2*w + jj;
      #pragma unroll
      for (int k=0;k<8;k++) wdec2[jj][k] = W_dec[(size_t)zr*DUNITS + 64*k + lane];
    }
    // bootstrap state (x=0,h=0,c=0): gates = bias (i: m=jj, g: m=4+jj, o: m=6+jj)
    float c_st[2], y_st[2];
    #pragma unroll
    for (int jj=0;jj<2;jj++){
      c_st[jj] = sigmoidf_(bias[jj])   * tanhf(bias[4+jj]);
      y_st[jj] = sigmoidf_(bias[6+jj]) * tanhf(c_st[jj]);
    }
    if (lane < 2){
      const float yv = (lane==0) ? y_st[0] : y_st[1];
      astoreu64(&ybuf[8*d + 2*w + lane], ((u64)1u<<32) | (u64)__float_as_uint(yv));
    }
    // wait for hp writers (all NBLK blocks)
    for(;;){
      const u32 d0 = aloadu32(&done[lane]);
      const u32 d1 = aloadu32(&done[64+lane]);
      const u32 d2 = (lane < NBLK-128) ? aloadu32(&done[128+lane]) : MAGIC;
      if (__all((d0==MAGIC) & (d1==MAGIC) & (d2==MAGIC))) break;
    }

    for (int t=0;t<TMAX;t++){
      const u32 tg = (u32)(t+1);
      // hp value for our z-row (issues before the poll)
      const float hpv = aloadf(&hp[(size_t)t*JOINT + 8*d + 2*w + (lane&1)]);
      // ---- wave0 polls y(t), broadcasts via LDS ----
      if (w == 0){
        float yp[8]; pollbuf8(ybuf + (t&1)*512, lane, tg, yp);
        #pragma unroll
        for (int j=0;j<8;j++) YL[64*j + lane] = yp[j];
      }
      __syncthreads();
      float y8[8];
      #pragma unroll
      for (int j=0;j<8;j++) y8[j] = YL[64*j + lane];
      // ---- critical: publish z(t) to 4 replicas ----
      float zz[2];
      #pragma unroll
      for (int jj=0;jj<2;jj++){
        float a=0.f;
        #pragma unroll
        for (int k=0;k<8;k++) a = fmaf(wdec2[jj][k], y8[k], a);
        zz[jj] = wredsum(a);
      }
      if (lane < 2){
        const float uv = (lane==0) ? zz[0] : zz[1];
        const u64 zw = ((u64)tg<<32) | (u64)__float_as_uint(tanhf(hpv + uv));
        const int zi = (t&1)*512 + 8*d + 2*w + lane;
        #pragma unroll
        for (int r=0;r<4;r++) astoreu64(&zrep[r*1024 + zi], zw);
      }
      // ---- off-critical: W_hh @ y (overlaps z->packs latency) ----
      float gt[8];
      #pragma unroll
      for (int m=0;m<8;m++){
        float a=0.f;
        #pragma unroll
        for (int k=0;k<8;k++) a = fmaf(whh[m][k], y8[k], a);
        gt[m] = wredsum(a) + bias[m];
      }
      // ---- wave0 polls packs(t), broadcasts pred ----
      if (w == 0){
        const u64* pk_s = packs + (t & RMASK)*128;
        u64 p0, p1;
        const u64 dummy = ((u64)tg << 48);
        for(;;){
          p0 = aloadu64(&pk_s[lane]);
          p1 = (lane < N_CONS-64) ? aloadu64(&pk_s[64+lane]) : dummy;
          if (__all(((u32)(p0>>48)==tg) & ((u32)(p1>>48)==tg))) break;
        }
        u64 best = (p0>p1)?p0:p1;
        best = wredmax64(best);
        if (lane==0) *PRD = (int)((~(u32)best) & 0xFFFFu);
      }
      __syncthreads();
      const int pred = *PRD;
      const int emitted = (pred != 0);
      // ---- gates += W_ih @ embed[pred]; nonlinearity; publish y(t+1) ----
      float e8[8];
      #pragma unroll
      for (int k=0;k<8;k++) e8[k] = embed[(size_t)pred*EMBED + 64*k + lane];
      #pragma unroll
      for (int m=0;m<8;m++){
        float a=0.f;
        #pragma unroll
        for (int k=0;k<8;k++) a = fmaf(wih[m][k], e8[k], a);
        gt[m] += wredsum(a);
      }
      #pragma unroll
      for (int jj=0;jj<2;jj++){
        const float gi=gt[jj], gf=gt[2+jj], gg=gt[4+jj], go=gt[6+jj];
        const float cn = sigmoidf_(gf)*c_st[jj] + sigmoidf_(gi)*tanhf(gg);
        const float yn = sigmoidf_(go)*tanhf(cn);
        if (emitted){ c_st[jj]=cn; y_st[jj]=yn; }
      }
      if (t+1 < TMAX && lane < 2){
        const float yv = (lane==0) ? y_st[0] : y_st[1];
        astoreu64(&ybuf[((t+1)&1)*512 + 8*d + 2*w + lane],
                  ((u64)(tg+1)<<32) | (u64)__float_as_uint(yv));
      }
    }
  }
  // ============================ role: SCORER =================================
  else if (b == B_SCORE){
    if (w == 0){
      float score = 0.0f;
      for (int t=0;t<TMAX;t++){
        const u32 tg = (u32)(t+1);
        const u64* pk_s = packs + (t & RMASK)*128;
        const u64* sm_s = sums  + (t & RMASK)*128;
        u64 p0=0,p1=0,s0=0,s1=0;
        const int v1 = (lane < N_CONS-64);
        for(;;){
          p0 = aloadu64(&pk_s[lane]);   s0 = aloadu64(&sm_s[lane]);
          int ok = ((u32)(p0>>48)==tg) & ((u32)(s0>>32)==tg);
          if (v1){
            p1 = aloadu64(&pk_s[64+lane]); s1 = aloadu64(&sm_s[64+lane]);
            ok &= ((u32)(p1>>48)==tg) & ((u32)(s1>>32)==tg);
          }
          if (__all(ok)) break;
          __builtin_amdgcn_s_sleep(8);
        }
        u64 best = (p0>p1)?p0:p1;
        best = wredmax64(best);
        const float mstar = unordbits((u32)(best>>16));
        const int pred = (int)((~(u32)best) & 0xFFFFu);
        float term = __uint_as_float((u32)s0) * __expf(unordbits((u32)(p0>>16)) - mstar);
        if (v1) term += __uint_as_float((u32)s1) * __expf(unordbits((u32)(p1>>16)) - mstar);
        term = wredsum(term);
        if (pred != 0) score += -logf(term);
        if (lane==0){
          out[t] = (float)pred;
          astoreu32(sprog, tg);          // ring overwrite gate progress
        }
      }
      if (lane==0) out[TMAX] = score;
    }
  }
  // ============================ role: CONSUMER ===============================
  else {
    const int cb = b - B_CONS0;
    const int rowstart = cb*80 + w*RPW;
    const u64* myrep = zrep + (cb & 3)*1024;
    float wout[RPW][8]; float bo[RPW];
    #pragma unroll
    for (int q=0;q<RPW;q++){
      const int r = rowstart + q;
      #pragma unroll
      for (int k=0;k<8;k++) wout[q][k] = W_out[(size_t)r*JOINT + 64*k + lane];
      bo[q] = b_out[r];
    }
    for (int t=0;t<TMAX;t++){
      const u32 tg = (u32)(t+1);
      if (w == 0){
        float zs[8]; pollbuf8(myrep + (t&1)*512, lane, tg, zs);
        #pragma unroll
        for (int j=0;j<8;j++) ZL[64*j + lane] = zs[j];
      }
      __syncthreads();
      float z8[8];
      #pragma unroll
      for (int j=0;j<8;j++) z8[j] = ZL[64*j + lane];
      float lg[RPW];
      #pragma unroll
      for (int q=0;q<RPW;q++){
        float a=0.f;
        #pragma unroll
        for (int k=0;k<8;k++) a = fmaf(wout[q][k], z8[k], a);
        lg[q] = wredsum(a) + bo[q];
      }
      u64 bk = 0;
      #pragma unroll
      for (int q=0;q<RPW;q++){
        const u64 key = ((u64)ordbits(lg[q])<<16) | (u64)(0xFFFFu & ~(u32)(rowstart+q));
        bk = (key>bk)?key:bk;
      }
      const float mw = unordbits((u32)(bk>>16));
      float sw = 0.f;
      #pragma unroll
      for (int q=0;q<RPW;q++) sw += __expf(lg[q]-mw);
      if (lane==0){ R64[w] = bk; RF[w] = sw; }
      __syncthreads();
      if (tid==0){
        u64 bb = R64[0];
        #pragma unroll
        for (int k=1;k<4;k++) bb = (R64[k]>bb)?R64[k]:bb;
        const float mb = unordbits((u32)(bb>>16));
        float S = 0.f;
        #pragma unroll
        for (int k=0;k<4;k++) S += RF[k]*__expf(unordbits((u32)(R64[k]>>16)) - mb);
        // ring overwrite gate: scorer must have finished step t-4's slot
        while ((int)aloadu32(sprog) < t-3){ __builtin_amdgcn_s_sleep(4); }
        const int slot = t & RMASK;
        astoreu64(&sums [slot*128 + cb], ((u64)tg<<32) | (u64)__float_as_uint(S));
        astoreu64(&packs[slot*128 + cb], ((u64)tg<<48) | bb);
      }
    }
  }
}

extern "C" void kernel_launch(void* const* d_in, const int* in_sizes, int n_in,
                              void* d_out, int out_size, void* d_ws, size_t ws_size,
                              hipStream_t stream)
{
  const float* h     = (const float*)d_in[0];
  const float* embed = (const float*)d_in[1];
  const float* W_ih  = (const float*)d_in[2];
  const float* W_hh  = (const float*)d_in[3];
  const float* b_ih  = (const float*)d_in[4];
  const float* b_hh  = (const float*)d_in[5];
  const float* W_enc = (const float*)d_in[6];
  const float* b_enc = (const float*)d_in[7];
  const float* W_dec = (const float*)d_in[8];
  const float* W_out = (const float*)d_in[9];
  const float* b_out = (const float*)d_in[10];
  float* out = (float*)d_out;
  char* ws = (char*)d_ws;

  hipLaunchKernelGGL(rnnt_init, dim3(1), dim3(NT), 0, stream, ws);
  hipLaunchKernelGGL(rnnt_decode, dim3(NBLK), dim3(NT), 0, stream,
                     h, embed, W_ih, W_hh, b_ih, b_hh, W_enc, b_enc, W_dec, W_out, b_out,
                     out, ws);
}